// Round 12
// baseline (603.107 us; speedup 1.0000x reference)
//
#include <hip/hip_runtime.h>
#include <cfloat>

#define NROWS  32768
#define NCODES 8192
#define DDIM   256
#define KG     4                 // code-split; grid = 128 row-tiles * 4 = 512 blocks
#define CPB    (NCODES / KG)     // 2048 codes per block
#define CT     64                // codes per stage (32 KB tile), double-buffered
#define TPB    (CPB / CT)        // 32 stages per block
#define RPB    256               // rows per block (4 waves x 64 rows)

typedef __attribute__((ext_vector_type(8)))  __bf16 bf16x8;
typedef __attribute__((ext_vector_type(16))) float  f32x16;

// ---- kernel A: codebook fp32 -> bf16 + fused esq (+1.0 bias for key-packing) ----
// esq' = ||e||^2 + 1 puts MFMA score s = esq' - 2 z.e in ~[0.56, 1.45]:
// strictly positive floats compare monotonically as u32 -> packed
// (score|index) argmin key in kernel B.
__global__ __launch_bounds__(256)
void cvt_cb(const float* __restrict__ cb, __bf16* __restrict__ cbb,
            float* __restrict__ esq) {
    const size_t i = (size_t)(blockIdx.x * 256 + threadIdx.x) * 8;
    const float4 f0 = *(const float4*)(cb + i);
    const float4 f1 = *(const float4*)(cb + i + 4);
    bf16x8 v;
    v[0] = (__bf16)f0.x; v[1] = (__bf16)f0.y; v[2] = (__bf16)f0.z; v[3] = (__bf16)f0.w;
    v[4] = (__bf16)f1.x; v[5] = (__bf16)f1.y; v[6] = (__bf16)f1.z; v[7] = (__bf16)f1.w;
    *(bf16x8*)(cbb + i) = v;
    float s = f0.x * f0.x + f0.y * f0.y + f0.z * f0.z + f0.w * f0.w
            + f1.x * f1.x + f1.y * f1.y + f1.z * f1.z + f1.w * f1.w;
    for (int o = 16; o > 0; o >>= 1) s += __shfl_down(s, o, 32);
    if ((threadIdx.x & 31) == 0) esq[i >> 8] = s + 1.0f;
}

// ---- kernel B: 32x32x16 + cross-half pipelined argmin (spill-managed) ----
// Post-mortem R11: serial per-wave chain (MFMA -> wait -> argmin -> init)
// leaves ~3k cyc/stage idle; antiphase between sibling blocks is not
// enforced. Fix: R6-style pipelined argmin at 32x32 -- argmin of the
// OTHER half's acc sits right after each MFMA cluster (independent of the
// in-flight MFMAs -> interleaves into the issue stream). R8's spill is
// avoided by scheduling staging into the accQ-dead window and C-initing
// via a shared einit register (first MFMA does the broadcast; saves 32
// movs/stage). Peak regs ~234 < 256 (2 waves/SIMD cap). Packed keys are
// order-independent (col bits break ties) so reordered argmin is exact.
// Geometry unchanged: 256 thr, 4 waves x 64 rows, KG=4, 2 blocks/CU,
// CT=64 dbuf, piece staging (1KB pieces, lane-matched, conflict-free).
__global__ __launch_bounds__(256, 2)
void vq_mfma(const float* __restrict__ z, const __bf16* __restrict__ cbb,
             const float* __restrict__ esq, unsigned* __restrict__ pK) {
    __shared__ __align__(16) __bf16 Bb[2][CT * DDIM];   // 2 x 32 KB

    const int rowbase  = (blockIdx.x >> 2) * RPB;
    const int kg       = blockIdx.x & 3;
    const int codebase = kg * CPB;

    const int tid = threadIdx.x;
    const int w = tid >> 6, l = tid & 63;       // wave = row-group (64 rows)
    const int la = l & 31, lh = l >> 5;
    const int loff = la * DDIM + lh * 8;        // lane offset in a 32-code group

    // ---- stage 0 loads first (overlap with A conversion below) ----
    // piece p (1 KB) = cols (p>>4)*32..+31, k (p&15)*16..+15. Wave w stages
    // pieces w*8..w*8+7; lane l supplies col la, k-half lh -> LDS dest =
    // p*1024 + l*16 B (read-matched, conflict-free).
#pragma unroll
    for (int jj = 0; jj < 8; ++jj) {
        const int p = w * 8 + jj;
        const int fc = p >> 4, kc = p & 15;
        __builtin_amdgcn_global_load_lds(
            (const __attribute__((address_space(1))) void*)
                (cbb + (size_t)(codebase + fc * 32) * DDIM + kc * 16 + loff),
            (__attribute__((address_space(3))) void*)(&Bb[0][p * 512]),
            16, 0, 0);
    }

    // ---- A prologue: 64 rows x 256 k -> Af[2][16] bf16x8 (-2*z), 128 VGPRs ----
    bf16x8 Af[2][16];   // [row-frag s (32 rows)][k-chunk kc (16 k)]
    {
        const float* zp = z + (size_t)(rowbase + w * 64 + la) * DDIM + lh * 8;
#pragma unroll
        for (int s = 0; s < 2; ++s)
#pragma unroll
            for (int kc = 0; kc < 16; ++kc) {
                const float4 f0 = *(const float4*)(zp + s * 32 * DDIM + kc * 16);
                const float4 f1 = *(const float4*)(zp + s * 32 * DDIM + kc * 16 + 4);
                bf16x8 v;
                v[0] = (__bf16)(-2.f * f0.x); v[1] = (__bf16)(-2.f * f0.y);
                v[2] = (__bf16)(-2.f * f0.z); v[3] = (__bf16)(-2.f * f0.w);
                v[4] = (__bf16)(-2.f * f1.x); v[5] = (__bf16)(-2.f * f1.y);
                v[6] = (__bf16)(-2.f * f1.z); v[7] = (__bf16)(-2.f * f1.w);
                Af[s][kc] = v;
            }
    }

    // esq for stage 0 (ping-ponged; 2 regs per buffer)
    float evc[2], evn[2];
    evc[0] = esq[codebase + la];
    evc[1] = esq[codebase + 32 + la];

    unsigned bestK[32];   // slot s*16+r: row (r&3)+8*(r>>2)+4*lh of frag s
#pragma unroll
    for (int s = 0; s < 32; ++s) bestK[s] = 0xFFFFFFFFu;

    // persistent accQ (col-half 1); dummy 2.0f keys (0x40000000|c) lose to
    // every real key (scores <= ~1.45)
    f32x16 accQ0, accQ1;
#pragma unroll
    for (int r = 0; r < 16; ++r) { accQ0[r] = 2.f; accQ1[r] = 2.f; }
    unsigned pQcol = (unsigned)codebase;   // col base of accQ's pending argmin

    __syncthreads();   // stage 0 staged

    int buf = 0;
#pragma unroll 1
    for (int t = 0; t < TPB; ++t) {
        const __bf16* Bc = &Bb[buf][0];

        // ---- cluster P: cols 0-31; C-init via shared einit (1st MFMA copies) ----
        f32x16 einit;
#pragma unroll
        for (int r = 0; r < 16; ++r) einit[r] = evc[0];
        f32x16 accP0, accP1;
        __builtin_amdgcn_s_setprio(1);
        {
            const bf16x8 b = *(const bf16x8*)(Bc + l * 8);
            accP0 = __builtin_amdgcn_mfma_f32_32x32x16_bf16(Af[0][0], b, einit, 0, 0, 0);
            accP1 = __builtin_amdgcn_mfma_f32_32x32x16_bf16(Af[1][0], b, einit, 0, 0, 0);
        }
#pragma unroll
        for (int kc = 1; kc < 16; ++kc) {
            const bf16x8 b = *(const bf16x8*)(Bc + kc * 512 + l * 8);
            accP0 = __builtin_amdgcn_mfma_f32_32x32x16_bf16(Af[0][kc], b, accP0, 0, 0, 0);
            accP1 = __builtin_amdgcn_mfma_f32_32x32x16_bf16(Af[1][kc], b, accP1, 0, 0, 0);
        }
        __builtin_amdgcn_s_setprio(0);

        // ---- pipelined argmin on accQ (stage t-1, col-half 1) ----
        // independent of P's in-flight MFMAs -> interleaves into issue stream
        {
            const unsigned cQ = pQcol + (unsigned)la;
#pragma unroll
            for (int r = 0; r < 16; ++r) {
                const unsigned k0 = (__float_as_uint(accQ0[r]) & 0xFFFFE000u) | cQ;
                if (k0 < bestK[r])      bestK[r]      = k0;
                const unsigned k1 = (__float_as_uint(accQ1[r]) & 0xFFFFE000u) | cQ;
                if (k1 < bestK[16 + r]) bestK[16 + r] = k1;
            }
        }

        // ---- staging t+1 in the accQ-dead window (pressure valley) ----
        if (t + 1 < TPB) {
            const __bf16* base = cbb + (size_t)(codebase + (t + 1) * CT) * DDIM;
#pragma unroll
            for (int jj = 0; jj < 8; ++jj) {
                const int p = w * 8 + jj;
                const int fc = p >> 4, kc = p & 15;
                __builtin_amdgcn_global_load_lds(
                    (const __attribute__((address_space(1))) void*)
                        (base + (size_t)(fc * 32) * DDIM + kc * 16 + loff),
                    (__attribute__((address_space(3))) void*)(&Bb[buf ^ 1][p * 512]),
                    16, 0, 0);
            }
        }
        {   // prefetch next stage's esq (2 regs)
            const int tn = (t + 1) & (TPB - 1);
            evn[0] = esq[codebase + tn * CT + la];
            evn[1] = esq[codebase + tn * CT + 32 + la];
        }

        // ---- cluster Q: cols 32-63 ----
#pragma unroll
        for (int r = 0; r < 16; ++r) einit[r] = evc[1];
        __builtin_amdgcn_s_setprio(1);
        {
            const bf16x8 b = *(const bf16x8*)(Bc + 16 * 512 + l * 8);
            accQ0 = __builtin_amdgcn_mfma_f32_32x32x16_bf16(Af[0][0], b, einit, 0, 0, 0);
            accQ1 = __builtin_amdgcn_mfma_f32_32x32x16_bf16(Af[1][0], b, einit, 0, 0, 0);
        }
#pragma unroll
        for (int kc = 1; kc < 16; ++kc) {
            const bf16x8 b = *(const bf16x8*)(Bc + (16 + kc) * 512 + l * 8);
            accQ0 = __builtin_amdgcn_mfma_f32_32x32x16_bf16(Af[0][kc], b, accQ0, 0, 0, 0);
            accQ1 = __builtin_amdgcn_mfma_f32_32x32x16_bf16(Af[1][kc], b, accQ1, 0, 0, 0);
        }
        __builtin_amdgcn_s_setprio(0);
        pQcol = (unsigned)(codebase + t * CT + 32);

        // ---- pipelined argmin on accP (stage t, col-half 0) ----
        // independent of Q's in-flight MFMAs
        {
            const unsigned cP = (unsigned)(codebase + t * CT + la);
#pragma unroll
            for (int r = 0; r < 16; ++r) {
                const unsigned k0 = (__float_as_uint(accP0[r]) & 0xFFFFE000u) | cP;
                if (k0 < bestK[r])      bestK[r]      = k0;
                const unsigned k1 = (__float_as_uint(accP1[r]) & 0xFFFFE000u) | cP;
                if (k1 < bestK[16 + r]) bestK[16 + r] = k1;
            }
        }

        evc[0] = evn[0]; evc[1] = evn[1];

        __syncthreads();   // staging landed; drain covered by sibling block
        buf ^= 1;
    }

    // epilogue: argmin on the final accQ
    {
        const unsigned cQ = pQcol + (unsigned)la;
#pragma unroll
        for (int r = 0; r < 16; ++r) {
            const unsigned k0 = (__float_as_uint(accQ0[r]) & 0xFFFFE000u) | cQ;
            if (k0 < bestK[r])      bestK[r]      = k0;
            const unsigned k1 = (__float_as_uint(accQ1[r]) & 0xFFFFE000u) | cQ;
            if (k1 < bestK[16 + r]) bestK[16 + r] = k1;
        }
    }

    // cross-lane u32-min over the 32 col-lanes
#pragma unroll
    for (int s = 0; s < 32; ++s) {
#pragma unroll
        for (int m = 1; m < 32; m <<= 1) {
            const unsigned k2 = (unsigned)__shfl_xor((int)bestK[s], m);
            if (k2 < bestK[s]) bestK[s] = k2;
        }
    }
    // rows partition across waves: direct global writeout (lanes 0 and 32)
    if (la == 0) {
#pragma unroll
        for (int s = 0; s < 2; ++s)
#pragma unroll
            for (int r = 0; r < 16; ++r) {
                const int rl = w * 64 + s * 32 + (r & 3) + 8 * (r >> 2) + 4 * lh;
                pK[(size_t)(rowbase + rl) * KG + kg] = bestK[s * 16 + r];
            }
    }
}

// ---- kernel C: combine K-groups (u32 min), gather, STE out, loss partials ----
__global__ __launch_bounds__(256)
void vq_finalize(const float* __restrict__ z, const float* __restrict__ cb,
                 const unsigned* __restrict__ pK,
                 float* __restrict__ out, float* __restrict__ bsum) {
    __shared__ float sSum[4];
    __shared__ int   sIdx[4];
    const int tid = threadIdx.x;
    const int rw = tid >> 6, lane = tid & 63;
    const int row = blockIdx.x * 4 + rw;

    if (lane == 0) {  // u32 min over KG groups: value-min, smaller-index ties
        unsigned k = pK[row * KG];
#pragma unroll
        for (int q = 1; q < KG; ++q) {
            const unsigned k2 = pK[row * KG + q];
            if (k2 < k) k = k2;
        }
        sIdx[rw] = (int)(k & 0x1FFFu);
    }
    __syncthreads();
    const int idx = sIdx[rw];

    const float4 zv = *(const float4*)(z  + (size_t)row * DDIM + lane * 4);
    const float4 ev = *(const float4*)(cb + (size_t)idx * DDIM + lane * 4);
    float4 d, o;
    d.x = ev.x - zv.x; d.y = ev.y - zv.y; d.z = ev.z - zv.z; d.w = ev.w - zv.w;
    o.x = zv.x + d.x;  o.y = zv.y + d.y;  o.z = zv.z + d.z;  o.w = zv.w + d.w;
    *(float4*)(out + (size_t)row * DDIM + lane * 4) = o;

    float s = d.x * d.x + d.y * d.y + d.z * d.z + d.w * d.w;
    for (int off = 32; off > 0; off >>= 1) s += __shfl_down(s, off);
    if (lane == 0) sSum[rw] = s;
    __syncthreads();
    if (tid == 0) bsum[blockIdx.x] = sSum[0] + sSum[1] + sSum[2] + sSum[3];
}

// ---- kernel D: loss ----
__global__ __launch_bounds__(256)
void loss_final(const float* __restrict__ bsum, float* __restrict__ out) {
    __shared__ float red[4];
    const int tid = threadIdx.x;
    float s = 0.f;
    for (int i = tid; i < NROWS / 4; i += 256) s += bsum[i];
    for (int off = 32; off > 0; off >>= 1) s += __shfl_down(s, off);
    const int wv = tid >> 6, lane = tid & 63;
    if (lane == 0) red[wv] = s;
    __syncthreads();
    if (tid == 0) {
        const float tot = red[0] + red[1] + red[2] + red[3];
        out[(size_t)NROWS * DDIM] = tot * (1.25f / (float)((size_t)NROWS * DDIM));
    }
}

extern "C" void kernel_launch(void* const* d_in, const int* in_sizes, int n_in,
                              void* d_out, int out_size, void* d_ws, size_t ws_size,
                              hipStream_t stream) {
    const float* z  = (const float*)d_in[0];
    const float* cb = (const float*)d_in[1];
    float* out = (float*)d_out;

    // bf16 codebook staged at head of d_out (4 MB; consumed by vq_mfma
    // before vq_finalize overwrites the region)
    __bf16* cbf = (__bf16*)d_out;

    // workspace carve (~600 KB)
    float*    esq  = (float*)d_ws;               // 8192
    unsigned* pK   = (unsigned*)(esq + NCODES);  // 32768*4
    float*    bsum = (float*)(pK + NROWS * KG);  // 8192

    cvt_cb<<<NCODES * DDIM / 8 / 256, 256, 0, stream>>>(cb, cbf, esq);
    vq_mfma<<<(NROWS / RPB) * KG, 256, 0, stream>>>(z, cbf, esq, pK);
    vq_finalize<<<NROWS / 4, 256, 0, stream>>>(z, cb, pK, out, bsum);
    loss_final<<<1, 256, 0, stream>>>(bsum, out);
}

// Round 13
// 352.895 us; speedup vs baseline: 1.7090x; 1.7090x over previous
//
#include <hip/hip_runtime.h>
#include <cfloat>

#define NROWS  32768
#define NCODES 8192
#define DDIM   256
#define KG     4                 // code-split; grid = 128 row-tiles * 4 = 512 blocks
#define CPB    (NCODES / KG)     // 2048 codes per block
#define CW     16                // codes per wave-stage (wave-private 8 KB tile)
#define TPB    (CPB / CW)        // 128 stages per wave
#define RPB    256               // rows per block (4 waves x 64 rows)

typedef __attribute__((ext_vector_type(8))) __bf16 bf16x8;
typedef __attribute__((ext_vector_type(4))) float  f32x4;

// ---- kernel A: codebook fp32 -> bf16 + fused esq (+1.0 bias for key-packing) ----
// esq' = ||e||^2 + 1 puts MFMA score s = esq' - 2 z.e in ~[0.56, 1.45]:
// strictly positive floats compare monotonically as u32 -> packed
// (score|index) argmin key in kernel B.
__global__ __launch_bounds__(256)
void cvt_cb(const float* __restrict__ cb, __bf16* __restrict__ cbb,
            float* __restrict__ esq) {
    const size_t i = (size_t)(blockIdx.x * 256 + threadIdx.x) * 8;
    const float4 f0 = *(const float4*)(cb + i);
    const float4 f1 = *(const float4*)(cb + i + 4);
    bf16x8 v;
    v[0] = (__bf16)f0.x; v[1] = (__bf16)f0.y; v[2] = (__bf16)f0.z; v[3] = (__bf16)f0.w;
    v[4] = (__bf16)f1.x; v[5] = (__bf16)f1.y; v[6] = (__bf16)f1.z; v[7] = (__bf16)f1.w;
    *(bf16x8*)(cbb + i) = v;
    float s = f0.x * f0.x + f0.y * f0.y + f0.z * f0.z + f0.w * f0.w
            + f1.x * f1.x + f1.y * f1.y + f1.z * f1.z + f1.w * f1.w;
    for (int o = 16; o > 0; o >>= 1) s += __shfl_down(s, o, 32);
    if ((threadIdx.x & 31) == 0) esq[i >> 8] = s + 1.0f;
}

// ---- kernel B: BARRIER-FREE wave-private pipeline (16x16x32) ----
// Post-mortem R8/R12: 32x32 + 2 live acc sets ALWAYS spills (Af128+64+32+
// temps > 256). Post-mortem R9/R10/R11: idle ~3.4k cyc/stage is INVARIANT
// across sync structures -- the per-stage block-wide barrier itself
// (rendezvous + phase-locking) is the residual. Fix: no barriers in the
// loop. Each wave stages its OWN 16-code x 256-k slice (8 KB, dbuf 16 KB)
// via global_load_lds and syncs with its own counted vmcnt(8) -- waves
// free-run (attn-like regime: setprio pays, phase-lock impossible).
// Staging requests duplicate per wave (~512 MB) but are L2-served
// (codebook 4 MB, XCD-resident; ~58% of per-XCD L2 BW). Shape 16x16x32
// (16-col stages; +15% MFMA demand vs 32x32 -- the price for 8 KB tiles).
// esq in LDS (one prologue barrier only, keeps loop vmcnt count exact).
// Regs: Af 128 + acc 16 + bestK 16 + temps ~185 << 256 -> no spill.
// Geometry: 256 thr (4 waves x 64 rows), KG=4, grid 512 = 2 blocks/CU,
// LDS 72 KB/block.
__global__ __launch_bounds__(256, 2)
void vq_mfma(const float* __restrict__ z, const __bf16* __restrict__ cbb,
             const float* __restrict__ esq, unsigned* __restrict__ pK) {
    __shared__ __align__(16) __bf16 Bw[4][2][CW * DDIM];  // 4 waves x 2 x 8 KB
    __shared__ __align__(16) float  esqLds[CPB];          // 8 KB

    const int rowbase  = (blockIdx.x >> 2) * RPB;
    const int kg       = blockIdx.x & 3;
    const int codebase = kg * CPB;

    const int tid = threadIdx.x;
    const int w = tid >> 6, l = tid & 63;   // wave = row-group (64 rows)
    const int lm = l & 15, lq = l >> 4;
    // staging: piece j (1 KB) = 16 codes x k j*32..+31; lane l supplies
    // code lm, k-sub lq*8 (16 B). LDS dest = piece base + l*16 B
    // (HW lane scatter), read back at kc*512 + l*8 elems -> lane-matched.
    const int loff = lm * DDIM + lq * 8;

    // ---- stage 0 staging (wave-private; overlaps A conversion below) ----
#pragma unroll
    for (int j = 0; j < 8; ++j) {
        __builtin_amdgcn_global_load_lds(
            (const __attribute__((address_space(1))) void*)
                (cbb + (size_t)codebase * DDIM + j * 32 + loff),
            (__attribute__((address_space(3))) void*)(&Bw[w][0][j * 512]),
            16, 0, 0);
    }

    // ---- esq -> LDS once (block-shared; 8 floats per thread) ----
    {
        const float4 q0 = *(const float4*)(esq + codebase + tid * 8);
        const float4 q1 = *(const float4*)(esq + codebase + tid * 8 + 4);
        *(float4*)&esqLds[tid * 8]     = q0;
        *(float4*)&esqLds[tid * 8 + 4] = q1;
    }

    // ---- A prologue: 64 rows x 256 k -> Af[4][8] bf16x8 (-2*z), 128 VGPRs ----
    bf16x8 Af[4][8];   // [16-row seg s][32-k chunk kc]
    {
        const float* zp = z + (size_t)(rowbase + w * 64 + lm) * DDIM + lq * 8;
#pragma unroll
        for (int s = 0; s < 4; ++s)
#pragma unroll
            for (int kc = 0; kc < 8; ++kc) {
                const float4 f0 = *(const float4*)(zp + s * 16 * DDIM + kc * 32);
                const float4 f1 = *(const float4*)(zp + s * 16 * DDIM + kc * 32 + 4);
                bf16x8 v;
                v[0] = (__bf16)(-2.f * f0.x); v[1] = (__bf16)(-2.f * f0.y);
                v[2] = (__bf16)(-2.f * f0.z); v[3] = (__bf16)(-2.f * f0.w);
                v[4] = (__bf16)(-2.f * f1.x); v[5] = (__bf16)(-2.f * f1.y);
                v[6] = (__bf16)(-2.f * f1.z); v[7] = (__bf16)(-2.f * f1.w);
                Af[s][kc] = v;
            }
    }

    unsigned bestK[16];   // slot s*4+i: row s*16 + lq*4 + i
#pragma unroll
    for (int s = 0; s < 16; ++s) bestK[s] = 0xFFFFFFFFu;

    // ONE barrier total: esq visibility across waves (also drains stage-0
    // staging and prologue loads -- loop vmcnt counting starts clean).
    __syncthreads();

    int buf = 0;
#pragma unroll 1
    for (int t = 0; t < TPB; ++t) {
        // issue stage t+1 into the other wave-private buffer (its reads
        // finished last stage -- same wave, in-order consumption)
        if (t + 1 < TPB) {
            const __bf16* src = cbb + (size_t)(codebase + (t + 1) * CW) * DDIM;
#pragma unroll
            for (int j = 0; j < 8; ++j) {
                __builtin_amdgcn_global_load_lds(
                    (const __attribute__((address_space(1))) void*)(src + j * 32 + loff),
                    (__attribute__((address_space(3))) void*)(&Bw[w][buf ^ 1][j * 512]),
                    16, 0, 0);
            }
            // wait OWN stage-t loads (8 newest = t+1's stay in flight)
            asm volatile("s_waitcnt vmcnt(8)" ::: "memory");
        } else {
            asm volatile("s_waitcnt vmcnt(0)" ::: "memory");
        }

        const float e = esqLds[t * CW + lm];   // broadcast read, conflict-free
        f32x4 acc[4];
#pragma unroll
        for (int s = 0; s < 4; ++s) acc[s] = (f32x4){e, e, e, e};

        const __bf16* Bc = &Bw[w][buf][0];
        __builtin_amdgcn_s_setprio(1);
#pragma unroll
        for (int kc = 0; kc < 8; ++kc) {
            const bf16x8 b = *(const bf16x8*)(Bc + kc * 512 + l * 8);
#pragma unroll
            for (int s = 0; s < 4; ++s)
                acc[s] = __builtin_amdgcn_mfma_f32_16x16x32_bf16(
                    Af[s][kc], b, acc[s], 0, 0, 0);
        }
        __builtin_amdgcn_s_setprio(0);

        {   // packed-key argmin (cols ascend with t; strict < via u32 min)
            const unsigned cI = (unsigned)(codebase + t * CW + lm);
#pragma unroll
            for (int s = 0; s < 4; ++s)
#pragma unroll
                for (int i = 0; i < 4; ++i) {
                    const unsigned k = (__float_as_uint(acc[s][i]) & 0xFFFFE000u) | cI;
                    const int slot = s * 4 + i;
                    if (k < bestK[slot]) bestK[slot] = k;
                }
        }

        buf ^= 1;
    }

    // cross-lane u32-min over the 16 col-lanes (lane bits 0..3 = lm)
#pragma unroll
    for (int s = 0; s < 16; ++s) {
#pragma unroll
        for (int m = 1; m < 16; m <<= 1) {
            const unsigned k2 = (unsigned)__shfl_xor((int)bestK[s], m);
            if (k2 < bestK[s]) bestK[s] = k2;
        }
    }
    // rows are wave-private: direct global writeout
    if (lm == 0) {
#pragma unroll
        for (int s = 0; s < 16; ++s) {   // row = w*64 + (s>>2)*16 + lq*4 + (s&3)
            const int rl = w * 64 + (s >> 2) * 16 + lq * 4 + (s & 3);
            pK[(size_t)(rowbase + rl) * KG + kg] = bestK[s];
        }
    }
}

// ---- kernel C: combine K-groups (u32 min), gather, STE out, loss partials ----
__global__ __launch_bounds__(256)
void vq_finalize(const float* __restrict__ z, const float* __restrict__ cb,
                 const unsigned* __restrict__ pK,
                 float* __restrict__ out, float* __restrict__ bsum) {
    __shared__ float sSum[4];
    __shared__ int   sIdx[4];
    const int tid = threadIdx.x;
    const int rw = tid >> 6, lane = tid & 63;
    const int row = blockIdx.x * 4 + rw;

    if (lane == 0) {  // u32 min over KG groups: value-min, smaller-index ties
        unsigned k = pK[row * KG];
#pragma unroll
        for (int q = 1; q < KG; ++q) {
            const unsigned k2 = pK[row * KG + q];
            if (k2 < k) k = k2;
        }
        sIdx[rw] = (int)(k & 0x1FFFu);
    }
    __syncthreads();
    const int idx = sIdx[rw];

    const float4 zv = *(const float4*)(z  + (size_t)row * DDIM + lane * 4);
    const float4 ev = *(const float4*)(cb + (size_t)idx * DDIM + lane * 4);
    float4 d, o;
    d.x = ev.x - zv.x; d.y = ev.y - zv.y; d.z = ev.z - zv.z; d.w = ev.w - zv.w;
    o.x = zv.x + d.x;  o.y = zv.y + d.y;  o.z = zv.z + d.z;  o.w = zv.w + d.w;
    *(float4*)(out + (size_t)row * DDIM + lane * 4) = o;

    float s = d.x * d.x + d.y * d.y + d.z * d.z + d.w * d.w;
    for (int off = 32; off > 0; off >>= 1) s += __shfl_down(s, off);
    if (lane == 0) sSum[rw] = s;
    __syncthreads();
    if (tid == 0) bsum[blockIdx.x] = sSum[0] + sSum[1] + sSum[2] + sSum[3];
}

// ---- kernel D: loss ----
__global__ __launch_bounds__(256)
void loss_final(const float* __restrict__ bsum, float* __restrict__ out) {
    __shared__ float red[4];
    const int tid = threadIdx.x;
    float s = 0.f;
    for (int i = tid; i < NROWS / 4; i += 256) s += bsum[i];
    for (int off = 32; off > 0; off >>= 1) s += __shfl_down(s, off);
    const int wv = tid >> 6, lane = tid & 63;
    if (lane == 0) red[wv] = s;
    __syncthreads();
    if (tid == 0) {
        const float tot = red[0] + red[1] + red[2] + red[3];
        out[(size_t)NROWS * DDIM] = tot * (1.25f / (float)((size_t)NROWS * DDIM));
    }
}

extern "C" void kernel_launch(void* const* d_in, const int* in_sizes, int n_in,
                              void* d_out, int out_size, void* d_ws, size_t ws_size,
                              hipStream_t stream) {
    const float* z  = (const float*)d_in[0];
    const float* cb = (const float*)d_in[1];
    float* out = (float*)d_out;

    // bf16 codebook staged at head of d_out (4 MB; consumed by vq_mfma
    // before vq_finalize overwrites the region)
    __bf16* cbf = (__bf16*)d_out;

    // workspace carve (~600 KB)
    float*    esq  = (float*)d_ws;               // 8192
    unsigned* pK   = (unsigned*)(esq + NCODES);  // 32768*4
    float*    bsum = (float*)(pK + NROWS * KG);  // 8192

    cvt_cb<<<NCODES * DDIM / 8 / 256, 256, 0, stream>>>(cb, cbf, esq);
    vq_mfma<<<(NROWS / RPB) * KG, 256, 0, stream>>>(z, cbf, esq, pK);
    vq_finalize<<<NROWS / 4, 256, 0, stream>>>(z, cb, pK, out, bsum);
    loss_final<<<1, 256, 0, stream>>>(bsum, out);
}

// Round 14
// 241.333 us; speedup vs baseline: 2.4991x; 1.4623x over previous
//
#include <hip/hip_runtime.h>
#include <cfloat>

#define NROWS  32768
#define NCODES 8192
#define DDIM   256
#define KG     4                 // code-split; grid = 128 row-tiles * 4 = 512 blocks
#define CPB    (NCODES / KG)     // 2048 codes per block
#define CT     32                // codes per stage (16 KB tile), 3-slot ring
#define TPB    (CPB / CT)        // 64 stages per block
#define RPB    256               // rows per block (4 waves x 64 rows)

typedef __attribute__((ext_vector_type(8)))  __bf16 bf16x8;
typedef __attribute__((ext_vector_type(16))) float  f32x16;

// ---- kernel A: codebook fp32 -> bf16 + fused esq (+1.0 bias for key-packing) ----
// esq' = ||e||^2 + 1 puts MFMA score s = esq' - 2 z.e in ~[0.56, 1.45]:
// strictly positive floats compare monotonically as u32 -> packed
// (score|index) argmin key in kernel B.
__global__ __launch_bounds__(256)
void cvt_cb(const float* __restrict__ cb, __bf16* __restrict__ cbb,
            float* __restrict__ esq) {
    const size_t i = (size_t)(blockIdx.x * 256 + threadIdx.x) * 8;
    const float4 f0 = *(const float4*)(cb + i);
    const float4 f1 = *(const float4*)(cb + i + 4);
    bf16x8 v;
    v[0] = (__bf16)f0.x; v[1] = (__bf16)f0.y; v[2] = (__bf16)f0.z; v[3] = (__bf16)f0.w;
    v[4] = (__bf16)f1.x; v[5] = (__bf16)f1.y; v[6] = (__bf16)f1.z; v[7] = (__bf16)f1.w;
    *(bf16x8*)(cbb + i) = v;
    float s = f0.x * f0.x + f0.y * f0.y + f0.z * f0.z + f0.w * f0.w
            + f1.x * f1.x + f1.y * f1.y + f1.z * f1.z + f1.w * f1.w;
    for (int o = 16; o > 0; o >>= 1) s += __shfl_down(s, o, 32);
    if ((threadIdx.x & 31) == 0) esq[i >> 8] = s + 1.0f;
}

// ---- kernel B: counted-vmcnt 3-ring, NO per-stage drain (T4), 2 blocks/CU ----
// Post-mortem R13: sync-frequency axis fully mapped (CT=64 optimal, barrier-
// free loses). R11 residual model: MFMA 132k + VALU 71k + LDS 65k = 80% of
// 336k wall; the rest is the per-stage __syncthreads FULL vmcnt DRAIN
// (compiler emits s_waitcnt vmcnt(0) lgkmcnt(0) before s_barrier -- the
// m97-structure stall; T4's counted vmcnt removes it, +38-73% in m218).
// Never tested here with 2 blocks/CU: R1 had counted vmcnt at 1 block/CU
// (rendezvous idled the CU); R10 had CT=32 WITH drain. This kernel: CT=32
// 3-slot ring (48 KB + 8 KB esq = 56 KB -> 2 blocks/CU), prefetch distance
// 2: per stage issue 4 loads for t+2, compute t, `s_waitcnt vmcnt(4)
// lgkmcnt(0)` (t+1's loads landed a full stage ~2.5k cyc ago -> wait ~0;
// t+2's 4 stay in flight ACROSS the raw s_barrier -- no drain in loop).
// esq in LDS keeps the loop's vmcnt count exact. Discriminator vs R10:
// if the drain was the ~3k/stage fixed cost -> win; if rendezvous -> R10-
// like, revert R11. Regs: Af 128 + acc 32 + bestK 32 + temps ~225 < 256.
__global__ __launch_bounds__(256, 2)
void vq_mfma(const float* __restrict__ z, const __bf16* __restrict__ cbb,
             const float* __restrict__ esq, unsigned* __restrict__ pK) {
    __shared__ __align__(16) __bf16 Bb[3][CT * DDIM];   // 3 x 16 KB ring
    __shared__ __align__(16) float  esqLds[CPB];        // 8 KB

    const int rowbase  = (blockIdx.x >> 2) * RPB;
    const int kg       = blockIdx.x & 3;
    const int codebase = kg * CPB;

    const int tid = threadIdx.x;
    const int w = tid >> 6, l = tid & 63;       // wave = row-group (64 rows)
    const int la = l & 31, lh = l >> 5;
    const int loff = la * DDIM + lh * 8;        // lane offset in the 32-code tile
    // staging: piece kc (1 KB) = 32 cols x k kc*16..+15; wave w stages
    // kc = w*4..w*4+3; lane l supplies col la, k-half lh -> LDS dest =
    // kc*1024 + l*16 B, read back at kc*512 + l*8 elems (lane-matched).
    const int kcb = w * 4;

    // ---- prologue: stage 0 and 1 into ring slots 0/1 ----
#pragma unroll
    for (int s0 = 0; s0 < 2; ++s0) {
        const __bf16* src = cbb + (size_t)(codebase + s0 * CT) * DDIM;
#pragma unroll
        for (int jj = 0; jj < 4; ++jj) {
            const int kc = kcb + jj;
            __builtin_amdgcn_global_load_lds(
                (const __attribute__((address_space(1))) void*)(src + kc * 16 + loff),
                (__attribute__((address_space(3))) void*)(&Bb[s0][kc * 512]),
                16, 0, 0);
        }
    }

    // ---- esq -> LDS once (2048 floats; 8 per thread) ----
    {
        const float4 q0 = *(const float4*)(esq + codebase + tid * 8);
        const float4 q1 = *(const float4*)(esq + codebase + tid * 8 + 4);
        *(float4*)&esqLds[tid * 8]     = q0;
        *(float4*)&esqLds[tid * 8 + 4] = q1;
    }

    // ---- A prologue: 64 rows x 256 k -> Af[2][16] bf16x8 (-2*z), 128 VGPRs ----
    bf16x8 Af[2][16];   // [row-frag s (32 rows)][k-chunk kc (16 k)]
    {
        const float* zp = z + (size_t)(rowbase + w * 64 + la) * DDIM + lh * 8;
#pragma unroll
        for (int s = 0; s < 2; ++s)
#pragma unroll
            for (int kc = 0; kc < 16; ++kc) {
                const float4 f0 = *(const float4*)(zp + s * 32 * DDIM + kc * 16);
                const float4 f1 = *(const float4*)(zp + s * 32 * DDIM + kc * 16 + 4);
                bf16x8 v;
                v[0] = (__bf16)(-2.f * f0.x); v[1] = (__bf16)(-2.f * f0.y);
                v[2] = (__bf16)(-2.f * f0.z); v[3] = (__bf16)(-2.f * f0.w);
                v[4] = (__bf16)(-2.f * f1.x); v[5] = (__bf16)(-2.f * f1.y);
                v[6] = (__bf16)(-2.f * f1.z); v[7] = (__bf16)(-2.f * f1.w);
                Af[s][kc] = v;
            }
    }

    unsigned bestK[32];   // slot s*16+r: row (r&3)+8*(r>>2)+4*lh of frag s
#pragma unroll
    for (int s = 0; s < 32; ++s) bestK[s] = 0xFFFFFFFFu;

    // ONE full drain total (prologue staging + A-loads + esq writes), then
    // the loop's vmcnt bookkeeping is exact.
    asm volatile("s_waitcnt vmcnt(0) lgkmcnt(0)" ::: "memory");
    __builtin_amdgcn_s_barrier();

    int sc = 0;   // ring slot of stage t; t+2 goes to (sc+2)%3
#pragma unroll 1
    for (int t = 0; t < TPB; ++t) {
        // issue stage t+2 into slot (sc+2)%3 (its readers finished at the
        // barrier ending stage t-1; issue is after that barrier -> safe)
        if (t + 2 < TPB) {
            int sp = sc + 2; if (sp >= 3) sp -= 3;
            const __bf16* src = cbb + (size_t)(codebase + (t + 2) * CT) * DDIM;
#pragma unroll
            for (int jj = 0; jj < 4; ++jj) {
                const int kc = kcb + jj;
                __builtin_amdgcn_global_load_lds(
                    (const __attribute__((address_space(1))) void*)(src + kc * 16 + loff),
                    (__attribute__((address_space(3))) void*)(&Bb[sp][kc * 512]),
                    16, 0, 0);
            }
        }

        // ---- 32-col MFMA cluster, einit via first-MFMA broadcast ----
        const float e = esqLds[t * CT + la];   // 32 words, 2-lane broadcast: free
        f32x16 einit;
#pragma unroll
        for (int r = 0; r < 16; ++r) einit[r] = e;
        const __bf16* Bc = &Bb[sc][0];
        f32x16 acc0, acc1;
        __builtin_amdgcn_s_setprio(1);
        {
            const bf16x8 b = *(const bf16x8*)(Bc + l * 8);
            acc0 = __builtin_amdgcn_mfma_f32_32x32x16_bf16(Af[0][0], b, einit, 0, 0, 0);
            acc1 = __builtin_amdgcn_mfma_f32_32x32x16_bf16(Af[1][0], b, einit, 0, 0, 0);
        }
#pragma unroll
        for (int kc = 1; kc < 16; ++kc) {
            const bf16x8 b = *(const bf16x8*)(Bc + kc * 512 + l * 8);
            acc0 = __builtin_amdgcn_mfma_f32_32x32x16_bf16(Af[0][kc], b, acc0, 0, 0, 0);
            acc1 = __builtin_amdgcn_mfma_f32_32x32x16_bf16(Af[1][kc], b, acc1, 0, 0, 0);
        }
        __builtin_amdgcn_s_setprio(0);

        // counted wait: t+1's 4 loads (issued last stage) must be done;
        // t+2's 4 stay in flight ACROSS the barrier. NO drain in the loop.
        if (t + 2 < TPB)
            asm volatile("s_waitcnt vmcnt(4) lgkmcnt(0)" ::: "memory");
        else
            asm volatile("s_waitcnt vmcnt(0) lgkmcnt(0)" ::: "memory");
        __builtin_amdgcn_s_barrier();

        // ---- packed-key argmin after the barrier (acc matured during
        // rendezvous; overlaps other waves' next-stage MFMA issue) ----
        {
            const unsigned cI = (unsigned)(codebase + t * CT + la);
#pragma unroll
            for (int r = 0; r < 16; ++r) {
                const unsigned k0 = (__float_as_uint(acc0[r]) & 0xFFFFE000u) | cI;
                if (k0 < bestK[r])      bestK[r]      = k0;
                const unsigned k1 = (__float_as_uint(acc1[r]) & 0xFFFFE000u) | cI;
                if (k1 < bestK[16 + r]) bestK[16 + r] = k1;
            }
        }

        ++sc; if (sc >= 3) sc -= 3;
    }

    // cross-lane u32-min over the 32 col-lanes (masks 1..16 stay in-half)
#pragma unroll
    for (int s = 0; s < 32; ++s) {
#pragma unroll
        for (int m = 1; m < 32; m <<= 1) {
            const unsigned k2 = (unsigned)__shfl_xor((int)bestK[s], m);
            if (k2 < bestK[s]) bestK[s] = k2;
        }
    }
    // rows partition across waves: direct global writeout (lanes 0 and 32)
    if (la == 0) {
#pragma unroll
        for (int s = 0; s < 2; ++s)
#pragma unroll
            for (int r = 0; r < 16; ++r) {
                const int rl = w * 64 + s * 32 + (r & 3) + 8 * (r >> 2) + 4 * lh;
                pK[(size_t)(rowbase + rl) * KG + kg] = bestK[s * 16 + r];
            }
    }
}

// ---- kernel C: combine K-groups (u32 min), gather, STE out, loss partials ----
__global__ __launch_bounds__(256)
void vq_finalize(const float* __restrict__ z, const float* __restrict__ cb,
                 const unsigned* __restrict__ pK,
                 float* __restrict__ out, float* __restrict__ bsum) {
    __shared__ float sSum[4];
    __shared__ int   sIdx[4];
    const int tid = threadIdx.x;
    const int rw = tid >> 6, lane = tid & 63;
    const int row = blockIdx.x * 4 + rw;

    if (lane == 0) {  // u32 min over KG groups: value-min, smaller-index ties
        unsigned k = pK[row * KG];
#pragma unroll
        for (int q = 1; q < KG; ++q) {
            const unsigned k2 = pK[row * KG + q];
            if (k2 < k) k = k2;
        }
        sIdx[rw] = (int)(k & 0x1FFFu);
    }
    __syncthreads();
    const int idx = sIdx[rw];

    const float4 zv = *(const float4*)(z  + (size_t)row * DDIM + lane * 4);
    const float4 ev = *(const float4*)(cb + (size_t)idx * DDIM + lane * 4);
    float4 d, o;
    d.x = ev.x - zv.x; d.y = ev.y - zv.y; d.z = ev.z - zv.z; d.w = ev.w - zv.w;
    o.x = zv.x + d.x;  o.y = zv.y + d.y;  o.z = zv.z + d.z;  o.w = zv.w + d.w;
    *(float4*)(out + (size_t)row * DDIM + lane * 4) = o;

    float s = d.x * d.x + d.y * d.y + d.z * d.z + d.w * d.w;
    for (int off = 32; off > 0; off >>= 1) s += __shfl_down(s, off);
    if (lane == 0) sSum[rw] = s;
    __syncthreads();
    if (tid == 0) bsum[blockIdx.x] = sSum[0] + sSum[1] + sSum[2] + sSum[3];
}

// ---- kernel D: loss ----
__global__ __launch_bounds__(256)
void loss_final(const float* __restrict__ bsum, float* __restrict__ out) {
    __shared__ float red[4];
    const int tid = threadIdx.x;
    float s = 0.f;
    for (int i = tid; i < NROWS / 4; i += 256) s += bsum[i];
    for (int off = 32; off > 0; off >>= 1) s += __shfl_down(s, off);
    const int wv = tid >> 6, lane = tid & 63;
    if (lane == 0) red[wv] = s;
    __syncthreads();
    if (tid == 0) {
        const float tot = red[0] + red[1] + red[2] + red[3];
        out[(size_t)NROWS * DDIM] = tot * (1.25f / (float)((size_t)NROWS * DDIM));
    }
}

extern "C" void kernel_launch(void* const* d_in, const int* in_sizes, int n_in,
                              void* d_out, int out_size, void* d_ws, size_t ws_size,
                              hipStream_t stream) {
    const float* z  = (const float*)d_in[0];
    const float* cb = (const float*)d_in[1];
    float* out = (float*)d_out;

    // bf16 codebook staged at head of d_out (4 MB; consumed by vq_mfma
    // before vq_finalize overwrites the region)
    __bf16* cbf = (__bf16*)d_out;

    // workspace carve (~600 KB)
    float*    esq  = (float*)d_ws;               // 8192
    unsigned* pK   = (unsigned*)(esq + NCODES);  // 32768*4
    float*    bsum = (float*)(pK + NROWS * KG);  // 8192

    cvt_cb<<<NCODES * DDIM / 8 / 256, 256, 0, stream>>>(cb, cbf, esq);
    vq_mfma<<<(NROWS / RPB) * KG, 256, 0, stream>>>(z, cbf, esq, pK);
    vq_finalize<<<NROWS / 4, 256, 0, stream>>>(z, cb, pK, out, bsum);
    loss_final<<<1, 256, 0, stream>>>(bsum, out);
}